// Round 11
// baseline (317.650 us; speedup 1.0000x reference)
//
#include <hip/hip_runtime.h>
#include <hip/hip_bf16.h>

typedef __attribute__((ext_vector_type(8))) short bf16x8;
typedef __attribute__((ext_vector_type(4))) float f32x4;

#define B_SZ   1024
#define T_SZ   128
#define L_SZ   256
#define F_SZ   784
#define M_TOT  (B_SZ * T_SZ)            // 131072
#define BK     32
#define KSTEPS 25                       // ceil(784/32), tail zero-padded

#define WPRE_ELEMS (KSTEPS * 4 * L_SZ)  // 25600 bf16x8 elements
#define WPRE_BYTES (WPRE_ELEMS * 16)    // 409600
#define CDIFF_ELEMS (T_SZ * L_SZ)       // 32768
#define WS_NEED (WPRE_BYTES + CDIFF_ELEMS * 4)

__device__ __forceinline__ unsigned short f2bf(float f) {
    __hip_bfloat16 h = __float2bfloat16(f);   // RTNE
    return *reinterpret_cast<unsigned short*>(&h);
}

// ---------------- prep: W -> bf16 MFMA-fragment layout; cdiff = c0 - c1 ----
__global__ __launch_bounds__(256) void dn_prep(
    const float* __restrict__ W, const float* __restrict__ contrib,
    unsigned short* __restrict__ wpre, float* __restrict__ cdiff)
{
    const int gid = blockIdx.x * 256 + threadIdx.x;
    if (gid < WPRE_ELEMS) {
        const int leaf = gid & 255;
        const int kg   = (gid >> 8) & 3;
        const int ks   = gid >> 10;
        const int k0   = ks * BK + kg * 8;
        bf16x8 v;
        #pragma unroll
        for (int j = 0; j < 8; ++j) {
            const int k = k0 + j;
            const float f = (k < F_SZ) ? W[(size_t)leaf * F_SZ + k] : 0.f;
            v[j] = (short)f2bf(f);
        }
        *reinterpret_cast<bf16x8*>(wpre + (size_t)gid * 8) = v;
    } else {
        const int cid = gid - WPRE_ELEMS;
        if (cid < CDIFF_ELEMS)
            cdiff[cid] = contrib[(size_t)cid * 2] - contrib[(size_t)cid * 2 + 1];
    }
}

// ---------------- v10: asm-pinned streaming pipeline, no barriers ----------
// Wave = 32 rows x 64 cols; 4 waves/block (128 rows x 64 cols); grid 4096 =
// 1024 rowGroups x 4 col-quarters, quarters of one rowGroup on the SAME XCD
// (bid&7 fixed) -> x HBM-read ~once, reuse via that XCD's L2/L3.
// ALL K-loop loads are inline-asm global_load_dwordx4 into a 3-slot register
// ring; counted s_waitcnt vmcnt(16) drains only the OLDEST group (2 groups =
// ~2-3 iters stay in flight, covering ~900cy HBM latency). asm volatile is
// order-pinned: the compiler cannot sink the issues (v4/v5/v9 failure mode).
// sched_barrier(0) after each wait stops MFMA/cvt hoisting above it (rule 18).
// Epilogue: per-wave private LDS slab transpose -> full-line contiguous
// stores; ZERO __syncthreads in the kernel (waves fully independent).

#define GLD(dst, adr, OFFS)                                                  \
    asm volatile("global_load_dwordx4 %0, %1, off offset:" OFFS              \
                 : "=v"(dst) : "v"(adr))

#define ISSUE(k, XO, XO16) do {                                              \
    const unsigned long long _wk = wadr + (unsigned long long)(k) * 16384ull;\
    GLD(sw[(k) % 3][0], _wk, "0");                                           \
    GLD(sw[(k) % 3][1], _wk, "256");                                         \
    GLD(sw[(k) % 3][2], _wk, "512");                                         \
    GLD(sw[(k) % 3][3], _wk, "768");                                         \
    GLD(sx[(k) % 3][0], xadr0, XO);                                          \
    GLD(sx[(k) % 3][1], xadr0, XO16);                                        \
    GLD(sx[(k) % 3][2], xadr1, XO);                                          \
    GLD(sx[(k) % 3][3], xadr1, XO16);                                        \
} while (0)

// tail group k=24: x addr clamped in-bounds for kseg>=2 (values don't-care,
// multiplied by wpre's zero padding)
#define ISSUE_T() do {                                                       \
    const unsigned long long _wk = wadr + 24ull * 16384ull;                  \
    GLD(sw[24 % 3][0], _wk, "0");                                            \
    GLD(sw[24 % 3][1], _wk, "256");                                          \
    GLD(sw[24 % 3][2], _wk, "512");                                          \
    GLD(sw[24 % 3][3], _wk, "768");                                          \
    GLD(sx[24 % 3][0], xqadr0, "0");                                         \
    GLD(sx[24 % 3][1], xqadr0, "16");                                        \
    GLD(sx[24 % 3][2], xqadr1, "0");                                         \
    GLD(sx[24 % 3][3], xqadr1, "16");                                        \
} while (0)

#define CONSUME(k, CNT) do {                                                 \
    asm volatile("s_waitcnt vmcnt(" CNT ")" ::: "memory");                   \
    __builtin_amdgcn_sched_barrier(0);                                       \
    bf16x8 _a0, _a1;                                                         \
    _Pragma("unroll")                                                        \
    for (int _j = 0; _j < 4; ++_j) {                                         \
        _a0[_j]     = (short)f2bf(sx[(k) % 3][0][_j]);                       \
        _a0[4 + _j] = (short)f2bf(sx[(k) % 3][1][_j]);                       \
        _a1[_j]     = (short)f2bf(sx[(k) % 3][2][_j]);                       \
        _a1[4 + _j] = (short)f2bf(sx[(k) % 3][3][_j]);                       \
    }                                                                        \
    _Pragma("unroll")                                                        \
    for (int _ni = 0; _ni < 4; ++_ni) {                                      \
        acc[0][_ni] = __builtin_amdgcn_mfma_f32_16x16x32_bf16(               \
            _a0, sw[(k) % 3][_ni], acc[0][_ni], 0, 0, 0);                    \
        acc[1][_ni] = __builtin_amdgcn_mfma_f32_16x16x32_bf16(               \
            _a1, sw[(k) % 3][_ni], acc[1][_ni], 0, 0, 0);                    \
    }                                                                        \
} while (0)

__global__ __launch_bounds__(256, 3) void dn_fused10(
    const float* __restrict__ x, const unsigned short* __restrict__ wpre,
    const float* __restrict__ bias, const float* __restrict__ cdiff,
    float* __restrict__ out)
{
    __shared__ float Ot[4][32][68];     // per-wave private slabs, 34.8 KB

    const int tid  = threadIdx.x;
    const int lane = tid & 63;
    const int wid  = tid >> 6;          // 0..3
    const int lr   = lane & 15;
    const int kseg = lane >> 4;         // 0..3

    const int bid = blockIdx.x;
    const int s   = bid >> 3;
    const int q   = s & 3;                        // col quarter
    const int rg  = (bid & 7) + 8 * (s >> 2);     // rowGroup 0..1023
    const int rowBlk  = rg * 128;
    const int rowBase = rowBlk + wid * 32;
    const int colBase = q * 64;

    const float* xp0 = x + (size_t)(rowBase + lr) * F_SZ + kseg * 8;
    const float* xp1 = xp0 + (size_t)16 * F_SZ;
    const int toff = (kseg < 2) ? 768 : -(kseg * 8);

    const unsigned long long xadr0  = (unsigned long long)(uintptr_t)xp0;
    const unsigned long long xadr1  = (unsigned long long)(uintptr_t)xp1;
    const unsigned long long xqadr0 = (unsigned long long)(uintptr_t)(xp0 + toff);
    const unsigned long long xqadr1 = (unsigned long long)(uintptr_t)(xp1 + toff);
    const unsigned long long wadr   = (unsigned long long)(uintptr_t)
        (wpre + ((size_t)kseg * L_SZ + colBase + lr) * 8);

    f32x4  sx[3][4];                    // x ring: 3 groups x 4 f32x4
    bf16x8 sw[3][4];                    // W ring: 3 groups x 4 bf16x8

    f32x4 acc[2][4];
    #pragma unroll
    for (int mi = 0; mi < 2; ++mi)
        #pragma unroll
        for (int ni = 0; ni < 4; ++ni)
            acc[mi][ni] = (f32x4){0.f, 0.f, 0.f, 0.f};

    // prologue: 3 groups in flight (24 VMEM instrs)
    ISSUE(0, "0", "16");
    ISSUE(1, "128", "144");
    ISSUE(2, "256", "272");

    CONSUME(0,  "16"); ISSUE(3,  "384",  "400");
    CONSUME(1,  "16"); ISSUE(4,  "512",  "528");
    CONSUME(2,  "16"); ISSUE(5,  "640",  "656");
    CONSUME(3,  "16"); ISSUE(6,  "768",  "784");
    CONSUME(4,  "16"); ISSUE(7,  "896",  "912");
    CONSUME(5,  "16"); ISSUE(8,  "1024", "1040");
    CONSUME(6,  "16"); ISSUE(9,  "1152", "1168");
    CONSUME(7,  "16"); ISSUE(10, "1280", "1296");
    CONSUME(8,  "16"); ISSUE(11, "1408", "1424");
    CONSUME(9,  "16"); ISSUE(12, "1536", "1552");
    CONSUME(10, "16"); ISSUE(13, "1664", "1680");
    CONSUME(11, "16"); ISSUE(14, "1792", "1808");
    CONSUME(12, "16"); ISSUE(15, "1920", "1936");
    CONSUME(13, "16"); ISSUE(16, "2048", "2064");
    CONSUME(14, "16"); ISSUE(17, "2176", "2192");
    CONSUME(15, "16"); ISSUE(18, "2304", "2320");
    CONSUME(16, "16"); ISSUE(19, "2432", "2448");
    CONSUME(17, "16"); ISSUE(20, "2560", "2576");
    CONSUME(18, "16"); ISSUE(21, "2688", "2704");
    CONSUME(19, "16"); ISSUE(22, "2816", "2832");
    CONSUME(20, "16"); ISSUE(23, "2944", "2960");
    CONSUME(21, "16"); ISSUE_T();
    CONSUME(22, "16");
    CONSUME(23, "8");
    CONSUME(24, "0");

    // ---- epilogue: sp/gini via per-wave LDS slab transpose (no barriers) --
    const size_t GOFF = (size_t)M_TOT * L_SZ;

    float spv[2][4][4];
    #pragma unroll
    for (int ni = 0; ni < 4; ++ni) {
        const float bb = bias[colBase + ni * 16 + lr];
        #pragma unroll
        for (int mi = 0; mi < 2; ++mi)
            #pragma unroll
            for (int r = 0; r < 4; ++r)
                spv[mi][ni][r] = fminf(fmaxf(acc[mi][ni][r] + bb, -1.f), 1.f);
    }

    // pass 1: sp -> slab -> contiguous store (256B runs per 16 lanes)
    #pragma unroll
    for (int ni = 0; ni < 4; ++ni)
        #pragma unroll
        for (int mi = 0; mi < 2; ++mi)
            #pragma unroll
            for (int r = 0; r < 4; ++r)
                Ot[wid][mi * 16 + kseg * 4 + r][ni * 16 + lr] = spv[mi][ni][r];
    #pragma unroll
    for (int j = 0; j < 8; ++j) {
        const int c   = lane + 64 * j;
        const int row = c >> 4;
        const int qd  = c & 15;
        const f32x4 v = *reinterpret_cast<const f32x4*>(&Ot[wid][row][qd * 4]);
        *reinterpret_cast<f32x4*>(out + (size_t)(rowBase + row) * L_SZ
                                  + colBase + qd * 4) = v;
    }

    // pass 2: gini -> slab -> contiguous store
    #pragma unroll
    for (int ni = 0; ni < 4; ++ni) {
        const int col = colBase + ni * 16 + lr;
        #pragma unroll
        for (int mi = 0; mi < 2; ++mi)
            #pragma unroll
            for (int r = 0; r < 4; ++r) {
                const int t = (rowBase + mi * 16 + kseg * 4 + r) & (T_SZ - 1);
                const float d  = spv[mi][ni][r] * cdiff[t * L_SZ + col];
                const float ed = __expf(d);
                const float s2 = ed / (1.f + ed);
                Ot[wid][mi * 16 + kseg * 4 + r][ni * 16 + lr]
                    = fmaf(2.f * s2, 1.f - s2, 1.f);
            }
    }
    #pragma unroll
    for (int j = 0; j < 8; ++j) {
        const int c   = lane + 64 * j;
        const int row = c >> 4;
        const int qd  = c & 15;
        const f32x4 v = *reinterpret_cast<const f32x4*>(&Ot[wid][row][qd * 4]);
        *reinterpret_cast<f32x4*>(out + GOFF + (size_t)(rowBase + row) * L_SZ
                                  + colBase + qd * 4) = v;
    }
}

// ---------------- v1 fallback (no workspace needed) ------------------------
__global__ __launch_bounds__(512) void dn_fused_v1(
    const float* __restrict__ x, const float* __restrict__ W,
    const float* __restrict__ bias, const float* __restrict__ contrib,
    float* __restrict__ out)
{
    __shared__ bf16x8 As[4][128];
    __shared__ bf16x8 Bs[4][L_SZ];

    const int tid    = threadIdx.x;
    const int lane   = tid & 63;
    const int wid    = tid >> 6;
    const int waveM  = wid >> 2;
    const int waveN  = wid & 3;
    const int blkRow = blockIdx.x * 128;
    const int ar = tid >> 2;
    const int ak = (tid & 3) * 8;
    const int wr = tid >> 1;
    const int wk = (tid & 1) * 16;
    const int laneRow = lane & 15;
    const int kgrp    = lane >> 4;

    f32x4 acc[4][4];
    #pragma unroll
    for (int i = 0; i < 4; ++i)
        #pragma unroll
        for (int j = 0; j < 4; ++j)
            acc[i][j] = (f32x4){0.f, 0.f, 0.f, 0.f};

    const float* xrow = x + (size_t)(blkRow + ar) * F_SZ;
    const float* wrow = W + (size_t)wr * F_SZ;
    const f32x4 zf = {0.f, 0.f, 0.f, 0.f};

    f32x4 xa0 = *reinterpret_cast<const f32x4*>(xrow + ak);
    f32x4 xa1 = *reinterpret_cast<const f32x4*>(xrow + ak + 4);
    f32x4 wa0 = *reinterpret_cast<const f32x4*>(wrow + wk);
    f32x4 wa1 = *reinterpret_cast<const f32x4*>(wrow + wk + 4);
    f32x4 wa2 = *reinterpret_cast<const f32x4*>(wrow + wk + 8);
    f32x4 wa3 = *reinterpret_cast<const f32x4*>(wrow + wk + 12);

    for (int ks = 0; ks < KSTEPS; ++ks) {
        bf16x8 av, wv0, wv1;
        #pragma unroll
        for (int j = 0; j < 4; ++j) {
            av[j]      = (short)f2bf(xa0[j]);
            av[4 + j]  = (short)f2bf(xa1[j]);
            wv0[j]     = (short)f2bf(wa0[j]);
            wv0[4 + j] = (short)f2bf(wa1[j]);
            wv1[j]     = (short)f2bf(wa2[j]);
            wv1[4 + j] = (short)f2bf(wa3[j]);
        }
        As[ak >> 3][ar] = av;
        Bs[wk >> 3][wr] = wv0;
        Bs[(wk >> 3) + 1][wr] = wv1;
        __syncthreads();

        if (ks + 1 < KSTEPS) {
            const int kb = (ks + 1) * BK;
            if (kb + ak < F_SZ) {
                xa0 = *reinterpret_cast<const f32x4*>(xrow + kb + ak);
                xa1 = *reinterpret_cast<const f32x4*>(xrow + kb + ak + 4);
            } else { xa0 = zf; xa1 = zf; }
            if (kb + wk < F_SZ) {
                wa0 = *reinterpret_cast<const f32x4*>(wrow + kb + wk);
                wa1 = *reinterpret_cast<const f32x4*>(wrow + kb + wk + 4);
                wa2 = *reinterpret_cast<const f32x4*>(wrow + kb + wk + 8);
                wa3 = *reinterpret_cast<const f32x4*>(wrow + kb + wk + 12);
            } else { wa0 = zf; wa1 = zf; wa2 = zf; wa3 = zf; }
        }

        bf16x8 af[4], bfv[4];
        #pragma unroll
        for (int mi = 0; mi < 4; ++mi)
            af[mi] = As[kgrp][waveM * 64 + mi * 16 + laneRow];
        #pragma unroll
        for (int ni = 0; ni < 4; ++ni)
            bfv[ni] = Bs[kgrp][waveN * 64 + ni * 16 + laneRow];
        #pragma unroll
        for (int mi = 0; mi < 4; ++mi)
            #pragma unroll
            for (int ni = 0; ni < 4; ++ni)
                acc[mi][ni] = __builtin_amdgcn_mfma_f32_16x16x32_bf16(
                    af[mi], bfv[ni], acc[mi][ni], 0, 0, 0);
        __syncthreads();
    }

    const size_t GOFF  = (size_t)M_TOT * L_SZ;
    const int    rbase = waveM * 64 + (lane >> 4) * 4;
    const int    cbase = waveN * 64 + laneRow;
    #pragma unroll
    for (int ni = 0; ni < 4; ++ni) {
        const int col = cbase + ni * 16;
        const float bb = bias[col];
        #pragma unroll
        for (int mi = 0; mi < 4; ++mi) {
            #pragma unroll
            for (int r = 0; r < 4; ++r) {
                const int m = blkRow + rbase + mi * 16 + r;
                const int t = m & (T_SZ - 1);
                float v  = acc[mi][ni][r] + bb;
                float sp = fminf(fmaxf(v, -1.f), 1.f);
                const float* cp = contrib + (size_t)(t * L_SZ + col) * 2;
                const float d  = sp * (cp[0] - cp[1]);
                const float ed = __expf(d);
                const float s  = ed / (1.f + ed);
                const float g  = fmaf(2.f * s, 1.f - s, 1.f);
                const size_t o = (size_t)m * L_SZ + col;
                out[o]        = sp;
                out[GOFF + o] = g;
            }
        }
    }
}

extern "C" void kernel_launch(void* const* d_in, const int* in_sizes, int n_in,
                              void* d_out, int out_size, void* d_ws, size_t ws_size,
                              hipStream_t stream) {
    const float* x       = (const float*)d_in[0];
    const float* W       = (const float*)d_in[1];
    const float* bias    = (const float*)d_in[2];
    const float* contrib = (const float*)d_in[3];
    float* out = (float*)d_out;

    if (ws_size >= (size_t)WS_NEED && d_ws != nullptr) {
        unsigned short* wpre  = (unsigned short*)d_ws;
        float*          cdiff = (float*)((char*)d_ws + WPRE_BYTES);
        const int prep_threads = WPRE_ELEMS + CDIFF_ELEMS;
        dn_prep<<<(prep_threads + 255) / 256, 256, 0, stream>>>(W, contrib, wpre, cdiff);
        dn_fused10<<<4096, 256, 0, stream>>>(x, wpre, bias, cdiff, out);
    } else {
        dn_fused_v1<<<M_TOT / 128, 512, 0, stream>>>(x, W, bias, contrib, out);
    }
}

// Round 12
// 219.436 us; speedup vs baseline: 1.4476x; 1.4476x over previous
//
#include <hip/hip_runtime.h>
#include <hip/hip_bf16.h>

typedef __attribute__((ext_vector_type(8))) short bf16x8;
typedef __attribute__((ext_vector_type(4))) float f32x4;

#define B_SZ   1024
#define T_SZ   128
#define L_SZ   256
#define F_SZ   784
#define M_TOT  (B_SZ * T_SZ)            // 131072
#define BK     32
#define KSTEPS 25                       // ceil(784/32), tail zero-padded

#define WPRE_ELEMS (KSTEPS * 4 * L_SZ)  // 25600 bf16x8 elements
#define WPRE_BYTES (WPRE_ELEMS * 16)    // 409600
#define CDIFF_ELEMS (T_SZ * L_SZ)       // 32768
#define WS_NEED (WPRE_BYTES + CDIFF_ELEMS * 4)

__device__ __forceinline__ unsigned short f2bf(float f) {
    __hip_bfloat16 h = __float2bfloat16(f);   // RTNE
    return *reinterpret_cast<unsigned short*>(&h);
}

// ---------------- prep: W -> bf16 MFMA-fragment layout; cdiff = c0 - c1 ----
// wpre[ks][kgrp][leaf] : bf16x8 = W[leaf][ks*32+kgrp*8 .. +8), 0-padded tail
__global__ __launch_bounds__(256) void dn_prep(
    const float* __restrict__ W, const float* __restrict__ contrib,
    unsigned short* __restrict__ wpre, float* __restrict__ cdiff)
{
    const int gid = blockIdx.x * 256 + threadIdx.x;
    if (gid < WPRE_ELEMS) {
        const int leaf = gid & 255;
        const int kg   = (gid >> 8) & 3;
        const int ks   = gid >> 10;
        const int k0   = ks * BK + kg * 8;
        bf16x8 v;
        #pragma unroll
        for (int j = 0; j < 8; ++j) {
            const int k = k0 + j;
            const float f = (k < F_SZ) ? W[(size_t)leaf * F_SZ + k] : 0.f;
            v[j] = (short)f2bf(f);
        }
        *reinterpret_cast<bf16x8*>(wpre + (size_t)gid * 8) = v;
    } else {
        const int cid = gid - WPRE_ELEMS;
        if (cid < CDIFF_ELEMS)
            cdiff[cid] = contrib[(size_t)cid * 2] - contrib[(size_t)cid * 2 + 1];
    }
}

// ---------------- v11: DMA-staged windowed pipeline (m201 mechanics) -------
// BM=128 rows x BN=256 cols, BK=32, 512 thr = 8 waves (wave tile 64x64,
// 2M x 4N). LDS 64KB: A f32 window dbuf 2x16KB + W bf16 slice dbuf 2x16KB,
// BOTH staged by global_load_lds (async DMA, no staging VGPRs, no ds_write).
// K-iter: ISSUE(k+1) -> s_waitcnt vmcnt(4) -> s_barrier -> consume(k) ->
// s_barrier. Raw barriers never drain vmcnt, so next-step DMAs stay in
// flight across the barrier pair (the proven counted-vmcnt mechanism).
// x is staged as f32 and converted to bf16 at frag-read (VALU co-issues
// with MFMA). A-LDS is XOR-swizzled by pre-swizzling the per-lane DMA
// SOURCE address (LDS dest must stay linear); frag reads apply the same
// XOR -> conflict-free. Tail step 24: per-lane source clamp; wpre's zero
// padding annihilates the garbage lanes.
// W L2 traffic: 400KB per 128 rows = 4x less than the 32-row versions.

#define GLDS(g, l)                                                           \
    __builtin_amdgcn_global_load_lds(                                        \
        (const __attribute__((address_space(1))) void*)(g),                  \
        (__attribute__((address_space(3))) void*)(l), 16, 0, 0)

__global__ __launch_bounds__(512, 4) void dn_fused11(
    const float* __restrict__ x, const unsigned short* __restrict__ wpre,
    const float* __restrict__ bias, const float* __restrict__ cdiff,
    float* __restrict__ out)
{
    __shared__ __align__(16) unsigned char smem[65536];
    // A f32 window: [b*16384 .. +16384) = 128 rows x 128 B (32 k-f32/row)
    // W bf16 slice: [32768 + b*16384 .. +16384) = [kgrp][leaf] x 16B

    const int tid   = threadIdx.x;
    const int lane  = tid & 63;
    const int wid   = tid >> 6;          // 0..7
    const int lr    = lane & 15;
    const int kseg  = lane >> 4;         // 0..3
    const int waveM = wid >> 2;          // 0..1
    const int wN    = wid & 3;           // 0..3

    const int rowBase = blockIdx.x * 128;

    // ---- per-lane DMA source addresses (dest = uniform base + lane*16) ----
    const int s0  = wid * 2048 + lane * 16;        // slot byte, instr 0
    const int s1  = s0 + 1024;                     // instr 1
    const int r0  = s0 >> 7, r1 = s1 >> 7;         // A row for this slot
    const int og0 = (s0 & 127) ^ ((r0 & 7) << 4);  // swizzled k-byte in row
    const int og1 = (s1 & 127) ^ ((r1 & 7) << 4);

    const char* xA0 = (const char*)x + (size_t)(rowBase + r0) * 3136 + og0;
    const char* xA1 = (const char*)x + (size_t)(rowBase + r1) * 3136 + og1;
    // tail k=24: row bytes [3072, 3136) valid -> og<64; else clamp to row start
    const char* xA0t = (const char*)x + (size_t)(rowBase + r0) * 3136
                       + (og0 < 64 ? 3072 + og0 : 0);
    const char* xA1t = (const char*)x + (size_t)(rowBase + r1) * 3136
                       + (og1 < 64 ? 3072 + og1 : 0);

    const int wg0 = s0 ^ (((s0 >> 12) & 3) << 4);  // W swizzle (kgrp bits)
    const int wg1 = s1 ^ (((s1 >> 12) & 3) << 4);
    const char* wS0 = (const char*)wpre + wg0;
    const char* wS1 = (const char*)wpre + wg1;

    const int ldsA0 = wid * 2048;                  // within A buffer
    const int ldsA1 = ldsA0 + 1024;
    const int ldsW0 = 32768 + wid * 2048;          // within W region
    const int ldsW1 = ldsW0 + 1024;

    #define ISSUE_STEP(k) do {                                               \
        const int _b = ((k) & 1) * 16384;                                    \
        if ((k) < 24) {                                                      \
            GLDS(xA0 + (size_t)(k) * 128, smem + _b + ldsA0);                \
            GLDS(xA1 + (size_t)(k) * 128, smem + _b + ldsA1);                \
        } else {                                                             \
            GLDS(xA0t, smem + _b + ldsA0);                                   \
            GLDS(xA1t, smem + _b + ldsA1);                                   \
        }                                                                    \
        GLDS(wS0 + (size_t)(k) * 16384, smem + _b + ldsW0);                  \
        GLDS(wS1 + (size_t)(k) * 16384, smem + _b + ldsW1);                  \
    } while (0)

    f32x4 acc[4][4];
    #pragma unroll
    for (int mi = 0; mi < 4; ++mi)
        #pragma unroll
        for (int ni = 0; ni < 4; ++ni)
            acc[mi][ni] = (f32x4){0.f, 0.f, 0.f, 0.f};

    // prologue: stage step 0, drain once, publish
    ISSUE_STEP(0);
    asm volatile("s_waitcnt vmcnt(0)" ::: "memory");
    __builtin_amdgcn_s_barrier();

    #pragma unroll
    for (int k = 0; k < KSTEPS; ++k) {
        // issue k+1 (safe: buf[(k+1)&1] fully consumed before iter k-1's
        // trailing barrier, which we are past)
        if (k + 1 < KSTEPS) {
            ISSUE_STEP(k + 1);
            asm volatile("s_waitcnt vmcnt(4)" ::: "memory");  // step k landed
        } else {
            asm volatile("s_waitcnt vmcnt(0)" ::: "memory");
        }
        __builtin_amdgcn_s_barrier();      // everyone's step-k data visible

        const unsigned char* Ab = smem + (k & 1) * 16384;
        const unsigned char* Wb = Ab + 32768;

        bf16x8 wf[4];
        #pragma unroll
        for (int ni = 0; ni < 4; ++ni) {
            const int Lw = kseg * 4096 + (wN * 64 + ni * 16 + lr) * 16;
            wf[ni] = *reinterpret_cast<const bf16x8*>(Wb + (Lw ^ (kseg << 4)));
        }
        #pragma unroll
        for (int mi = 0; mi < 4; ++mi) {
            const int row = waveM * 64 + mi * 16 + lr;
            const int sw  = (row & 7) << 4;
            const f32x4 alo = *reinterpret_cast<const f32x4*>(
                Ab + row * 128 + ((kseg * 32) ^ sw));
            const f32x4 ahi = *reinterpret_cast<const f32x4*>(
                Ab + row * 128 + ((kseg * 32 + 16) ^ sw));
            bf16x8 af;
            #pragma unroll
            for (int j = 0; j < 4; ++j) {
                af[j]     = (short)f2bf(alo[j]);
                af[4 + j] = (short)f2bf(ahi[j]);
            }
            #pragma unroll
            for (int ni = 0; ni < 4; ++ni)
                acc[mi][ni] = __builtin_amdgcn_mfma_f32_16x16x32_bf16(
                    af, wf[ni], acc[mi][ni], 0, 0, 0);
        }
        __builtin_amdgcn_s_barrier();      // all reads of buf k done
    }
    #undef ISSUE_STEP

    // ---- epilogue: sp in regs; 4 quarter-tiles via LDS transpose ----
    float spv[4][4][4];
    #pragma unroll
    for (int ni = 0; ni < 4; ++ni) {
        const float bb = bias[wN * 64 + ni * 16 + lr];
        #pragma unroll
        for (int mi = 0; mi < 4; ++mi)
            #pragma unroll
            for (int r = 0; r < 4; ++r)
                spv[mi][ni][r] = fminf(fmaxf(acc[mi][ni][r] + bb, -1.f), 1.f);
    }

    typedef float OtRow[264];                      // +8 pad
    OtRow* Ot = reinterpret_cast<OtRow*>(smem);    // 32 x 264 x 4 = 33.8 KB

    const int erow = tid >> 4;          // 0..31
    const int ecol = (tid & 15) * 16;   // 0..240
    const size_t GOFF = (size_t)M_TOT * L_SZ;

    __syncthreads();                    // K-loop LDS dead; reuse as Ot

    #pragma unroll
    for (int q = 0; q < 4; ++q) {
        const int qrow = rowBase + q * 32;
        // pass 1: sp quarter -> Ot (writers: waves with waveM == q>>1)
        if (waveM == (q >> 1)) {
            #pragma unroll
            for (int m2 = 0; m2 < 2; ++m2) {
                const int mi = (q & 1) * 2 + m2;
                #pragma unroll
                for (int ni = 0; ni < 4; ++ni)
                    #pragma unroll
                    for (int r = 0; r < 4; ++r)
                        Ot[m2 * 16 + kseg * 4 + r][wN * 64 + ni * 16 + lr]
                            = spv[mi][ni][r];
            }
        }
        __syncthreads();
        #pragma unroll
        for (int j = 0; j < 4; ++j) {
            const f32x4 v = *reinterpret_cast<const f32x4*>(&Ot[erow][ecol + j * 4]);
            *reinterpret_cast<f32x4*>(out + (size_t)(qrow + erow) * L_SZ
                                      + ecol + j * 4) = v;
        }
        __syncthreads();
        // pass 2: gini quarter
        if (waveM == (q >> 1)) {
            #pragma unroll
            for (int m2 = 0; m2 < 2; ++m2) {
                const int mi = (q & 1) * 2 + m2;
                #pragma unroll
                for (int ni = 0; ni < 4; ++ni) {
                    const int col = wN * 64 + ni * 16 + lr;
                    #pragma unroll
                    for (int r = 0; r < 4; ++r) {
                        const int t = q * 32 + m2 * 16 + kseg * 4 + r; // row&127
                        const float d  = spv[mi][ni][r] * cdiff[t * L_SZ + col];
                        const float ed = __expf(d);
                        const float s2 = ed / (1.f + ed);
                        Ot[m2 * 16 + kseg * 4 + r][col]
                            = fmaf(2.f * s2, 1.f - s2, 1.f);
                    }
                }
            }
        }
        __syncthreads();
        #pragma unroll
        for (int j = 0; j < 4; ++j) {
            const f32x4 v = *reinterpret_cast<const f32x4*>(&Ot[erow][ecol + j * 4]);
            *reinterpret_cast<f32x4*>(out + GOFF + (size_t)(qrow + erow) * L_SZ
                                      + ecol + j * 4) = v;
        }
        __syncthreads();
    }
}

// ---------------- v1 fallback (no workspace needed) ------------------------
__global__ __launch_bounds__(512) void dn_fused_v1(
    const float* __restrict__ x, const float* __restrict__ W,
    const float* __restrict__ bias, const float* __restrict__ contrib,
    float* __restrict__ out)
{
    __shared__ bf16x8 As[4][128];
    __shared__ bf16x8 Bs[4][L_SZ];

    const int tid    = threadIdx.x;
    const int lane   = tid & 63;
    const int wid    = tid >> 6;
    const int waveM  = wid >> 2;
    const int waveN  = wid & 3;
    const int blkRow = blockIdx.x * 128;
    const int ar = tid >> 2;
    const int ak = (tid & 3) * 8;
    const int wr = tid >> 1;
    const int wk = (tid & 1) * 16;
    const int laneRow = lane & 15;
    const int kgrp    = lane >> 4;

    f32x4 acc[4][4];
    #pragma unroll
    for (int i = 0; i < 4; ++i)
        #pragma unroll
        for (int j = 0; j < 4; ++j)
            acc[i][j] = (f32x4){0.f, 0.f, 0.f, 0.f};

    const float* xrow = x + (size_t)(blkRow + ar) * F_SZ;
    const float* wrow = W + (size_t)wr * F_SZ;
    const f32x4 zf = {0.f, 0.f, 0.f, 0.f};

    f32x4 xa0 = *reinterpret_cast<const f32x4*>(xrow + ak);
    f32x4 xa1 = *reinterpret_cast<const f32x4*>(xrow + ak + 4);
    f32x4 wa0 = *reinterpret_cast<const f32x4*>(wrow + wk);
    f32x4 wa1 = *reinterpret_cast<const f32x4*>(wrow + wk + 4);
    f32x4 wa2 = *reinterpret_cast<const f32x4*>(wrow + wk + 8);
    f32x4 wa3 = *reinterpret_cast<const f32x4*>(wrow + wk + 12);

    for (int ks = 0; ks < KSTEPS; ++ks) {
        bf16x8 av, wv0, wv1;
        #pragma unroll
        for (int j = 0; j < 4; ++j) {
            av[j]      = (short)f2bf(xa0[j]);
            av[4 + j]  = (short)f2bf(xa1[j]);
            wv0[j]     = (short)f2bf(wa0[j]);
            wv0[4 + j] = (short)f2bf(wa1[j]);
            wv1[j]     = (short)f2bf(wa2[j]);
            wv1[4 + j] = (short)f2bf(wa3[j]);
        }
        As[ak >> 3][ar] = av;
        Bs[wk >> 3][wr] = wv0;
        Bs[(wk >> 3) + 1][wr] = wv1;
        __syncthreads();

        if (ks + 1 < KSTEPS) {
            const int kb = (ks + 1) * BK;
            if (kb + ak < F_SZ) {
                xa0 = *reinterpret_cast<const f32x4*>(xrow + kb + ak);
                xa1 = *reinterpret_cast<const f32x4*>(xrow + kb + ak + 4);
            } else { xa0 = zf; xa1 = zf; }
            if (kb + wk < F_SZ) {
                wa0 = *reinterpret_cast<const f32x4*>(wrow + kb + wk);
                wa1 = *reinterpret_cast<const f32x4*>(wrow + kb + wk + 4);
                wa2 = *reinterpret_cast<const f32x4*>(wrow + kb + wk + 8);
                wa3 = *reinterpret_cast<const f32x4*>(wrow + kb + wk + 12);
            } else { wa0 = zf; wa1 = zf; wa2 = zf; wa3 = zf; }
        }

        bf16x8 af[4], bfv[4];
        #pragma unroll
        for (int mi = 0; mi < 4; ++mi)
            af[mi] = As[kgrp][waveM * 64 + mi * 16 + laneRow];
        #pragma unroll
        for (int ni = 0; ni < 4; ++ni)
            bfv[ni] = Bs[kgrp][waveN * 64 + ni * 16 + laneRow];
        #pragma unroll
        for (int mi = 0; mi < 4; ++mi)
            #pragma unroll
            for (int ni = 0; ni < 4; ++ni)
                acc[mi][ni] = __builtin_amdgcn_mfma_f32_16x16x32_bf16(
                    af[mi], bfv[ni], acc[mi][ni], 0, 0, 0);
        __syncthreads();
    }

    const size_t GOFF  = (size_t)M_TOT * L_SZ;
    const int    rbase = waveM * 64 + (lane >> 4) * 4;
    const int    cbase = waveN * 64 + laneRow;
    #pragma unroll
    for (int ni = 0; ni < 4; ++ni) {
        const int col = cbase + ni * 16;
        const float bb = bias[col];
        #pragma unroll
        for (int mi = 0; mi < 4; ++mi) {
            #pragma unroll
            for (int r = 0; r < 4; ++r) {
                const int m = blkRow + rbase + mi * 16 + r;
                const int t = m & (T_SZ - 1);
                float v  = acc[mi][ni][r] + bb;
                float sp = fminf(fmaxf(v, -1.f), 1.f);
                const float* cp = contrib + (size_t)(t * L_SZ + col) * 2;
                const float d  = sp * (cp[0] - cp[1]);
                const float ed = __expf(d);
                const float s  = ed / (1.f + ed);
                const float g  = fmaf(2.f * s, 1.f - s, 1.f);
                const size_t o = (size_t)m * L_SZ + col;
                out[o]        = sp;
                out[GOFF + o] = g;
            }
        }
    }
}

extern "C" void kernel_launch(void* const* d_in, const int* in_sizes, int n_in,
                              void* d_out, int out_size, void* d_ws, size_t ws_size,
                              hipStream_t stream) {
    const float* x       = (const float*)d_in[0];
    const float* W       = (const float*)d_in[1];
    const float* bias    = (const float*)d_in[2];
    const float* contrib = (const float*)d_in[3];
    float* out = (float*)d_out;

    if (ws_size >= (size_t)WS_NEED && d_ws != nullptr) {
        unsigned short* wpre  = (unsigned short*)d_ws;
        float*          cdiff = (float*)((char*)d_ws + WPRE_BYTES);
        const int prep_threads = WPRE_ELEMS + CDIFF_ELEMS;
        dn_prep<<<(prep_threads + 255) / 256, 256, 0, stream>>>(W, contrib, wpre, cdiff);
        dn_fused11<<<M_TOT / 128, 512, 0, stream>>>(x, wpre, bias, cdiff, out);
    } else {
        dn_fused_v1<<<M_TOT / 128, 512, 0, stream>>>(x, W, bias, contrib, out);
    }
}

// Round 13
// 190.013 us; speedup vs baseline: 1.6717x; 1.1548x over previous
//
#include <hip/hip_runtime.h>
#include <hip/hip_bf16.h>

typedef __attribute__((ext_vector_type(8))) short bf16x8;
typedef __attribute__((ext_vector_type(4))) float f32x4;

#define B_SZ   1024
#define T_SZ   128
#define L_SZ   256
#define F_SZ   784
#define M_TOT  (B_SZ * T_SZ)            // 131072
#define BK     32
#define KSTEPS 25                       // ceil(784/32), tail zero-padded

#define WPRE_ELEMS (KSTEPS * 4 * L_SZ)  // 25600 bf16x8 elements
#define WPRE_BYTES (WPRE_ELEMS * 16)    // 409600
#define CDIFF_ELEMS (T_SZ * L_SZ)       // 32768
#define WS_NEED (WPRE_BYTES + CDIFF_ELEMS * 4)

// v12 geometry: A f32 window = 32 rows x 160 f32 (5 K-steps), row pitch 656B
#define ROWB   656                      // 640 data + 16 pad (bank rotation)
#define WINB   (32 * ROWB)              // 20992; buffer stride 21504 (21 instr)
#define BUFB   21504

__device__ __forceinline__ unsigned short f2bf(float f) {
    __hip_bfloat16 h = __float2bfloat16(f);   // RTNE
    return *reinterpret_cast<unsigned short*>(&h);
}

// ---------------- prep: W -> bf16 MFMA-fragment layout; cdiff = c0 - c1 ----
// wpre[ks][kgrp][leaf] : bf16x8 = W[leaf][ks*32+kgrp*8 .. +8), 0-padded tail
__global__ __launch_bounds__(256) void dn_prep(
    const float* __restrict__ W, const float* __restrict__ contrib,
    unsigned short* __restrict__ wpre, float* __restrict__ cdiff)
{
    const int gid = blockIdx.x * 256 + threadIdx.x;
    if (gid < WPRE_ELEMS) {
        const int leaf = gid & 255;
        const int kg   = (gid >> 8) & 3;
        const int ks   = gid >> 10;
        const int k0   = ks * BK + kg * 8;
        bf16x8 v;
        #pragma unroll
        for (int j = 0; j < 8; ++j) {
            const int k = k0 + j;
            const float f = (k < F_SZ) ? W[(size_t)leaf * F_SZ + k] : 0.f;
            v[j] = (short)f2bf(f);
        }
        *reinterpret_cast<bf16x8*>(wpre + (size_t)gid * 8) = v;
    } else {
        const int cid = gid - WPRE_ELEMS;
        if (cid < CDIFF_ELEMS)
            cdiff[cid] = contrib[(size_t)cid * 2] - contrib[(size_t)cid * 2 + 1];
    }
}

// ---------------- v12: coarse-window DMA pipeline, 6 barriers total --------
// Block = 32 rows x 256 cols, 512 thr, 8 waves (wave tile 32x32). Grid 4096.
// A is staged as f32 by global_load_lds into a 2x21KB windowed double buffer
// (5 K-steps per window, 5 windows). Per window: issue next window's DMAs
// (2-3 per wave, contiguous ~17-line sources), run 5 K-steps (W streamed
// from L2 with 1-deep reg prefetch, f32->bf16 cvt at frag read), then ONE
// vmcnt(0) + s_barrier. DMAs stay in flight under the whole window's
// compute -> x HBM stream overlaps MFMA + L2-W traffic, with 6 barriers
// per block instead of v11's 50 (m233 lockstep lesson) or v8's serial stage.
// Row pitch 656B rotates each row's bank start by 4 -> frag reads reproduce
// v8's measured-conflict-free pattern without XOR swizzles.
// LDS 42KB -> 3 blocks/CU (24 waves). Epilogue = v7's proven transpose.

#define GLDS(g, l)                                                           \
    __builtin_amdgcn_global_load_lds(                                        \
        (const __attribute__((address_space(1))) void*)(g),                  \
        (__attribute__((address_space(3))) void*)(l), 16, 0, 0)

__global__ __launch_bounds__(512, 6) void dn_fused12(
    const float* __restrict__ x, const unsigned short* __restrict__ wpre,
    const float* __restrict__ bias, const float* __restrict__ cdiff,
    float* __restrict__ out)
{
    __shared__ __align__(16) unsigned char smem[2 * BUFB];   // 43008 B

    const int tid  = threadIdx.x;
    const int lane = tid & 63;
    const int wid  = tid >> 6;          // 0..7 -> 32-col group
    const int lr   = lane & 15;
    const int kseg = lane >> 4;         // 0..3

    const int rowBase = blockIdx.x * 32;
    const int colBase = wid * 32;

    // ---- per-lane DMA sources: instr j covers dest bytes [j*1024, +1024) ----
    // dest layout: row = s/656, in-row byte = s%656 (640 data + 16 pad)
    const char* xb = (const char*)x;
    const char* srcB[3];   // window-0 source (add w*640 per window)
    const char* srcC[3];   // clamped: row start (for pad/tail lanes)
    bool        v4[3];     // window-4 validity (col < 784)
    #pragma unroll
    for (int jj = 0; jj < 3; ++jj) {
        const int j = wid + 8 * jj;
        const unsigned s    = j * 1024 + lane * 16;
        const unsigned row  = s / ROWB;
        const unsigned colb = s - row * ROWB;
        const bool     ok   = (row < 32) && (colb < 640);
        const unsigned rcl  = (row < 32) ? row : 0;
        srcC[jj] = xb + (size_t)(rowBase + rcl) * 3136;
        srcB[jj] = srcC[jj] + (ok ? colb : 0);
        v4[jj]   = ok && (colb < 576);           // 2560+colb < 3136
    }

    #define ISSUE(w) do {                                                    \
        _Pragma("unroll")                                                    \
        for (int _jj = 0; _jj < 3; ++_jj) {                                  \
            const int _j = wid + 8 * _jj;                                    \
            if (_j < 21) {                                                   \
                const char* _s = ((w) < 4) ? (srcB[_jj] + (w) * 640)         \
                                : (v4[_jj] ? srcB[_jj] + 2560 : srcC[_jj]);  \
                GLDS(_s, smem + ((w) & 1) * BUFB + _j * 1024);               \
            }                                                                \
        }                                                                    \
    } while (0)

    // ---- accumulators + W register stream ----
    f32x4 acc[2][2];
    #pragma unroll
    for (int mi = 0; mi < 2; ++mi)
        #pragma unroll
        for (int ni = 0; ni < 2; ++ni)
            acc[mi][ni] = (f32x4){0.f, 0.f, 0.f, 0.f};

    const unsigned short* wpb = wpre + ((size_t)kseg * L_SZ + colBase + lr) * 8;
    bf16x8 wcur[2], wnxt[2];

    // prologue: window 0 in flight, first W pair
    ISSUE(0);
    wcur[0] = *reinterpret_cast<const bf16x8*>(wpb);
    wcur[1] = *reinterpret_cast<const bf16x8*>(wpb + 128);
    asm volatile("s_waitcnt vmcnt(0)" ::: "memory");
    __builtin_amdgcn_s_barrier();

    #pragma unroll
    for (int w = 0; w < 5; ++w) {
        if (w < 4) ISSUE(w + 1);        // flies under this window's 5 K-steps

        const unsigned char* Ab = smem + (w & 1) * BUFB;
        #pragma unroll
        for (int i = 0; i < 5; ++i) {
            const int ks = w * 5 + i;
            if (ks + 1 < KSTEPS) {
                wnxt[0] = *reinterpret_cast<const bf16x8*>(wpb + (size_t)(ks + 1) * 8192);
                wnxt[1] = *reinterpret_cast<const bf16x8*>(wpb + (size_t)(ks + 1) * 8192 + 128);
            }
            bf16x8 af[2];
            #pragma unroll
            for (int m = 0; m < 2; ++m) {
                const int off = (m * 16 + lr) * ROWB + i * 128 + kseg * 32;
                const f32x4 alo = *reinterpret_cast<const f32x4*>(Ab + off);
                const f32x4 ahi = *reinterpret_cast<const f32x4*>(Ab + off + 16);
                #pragma unroll
                for (int jd = 0; jd < 4; ++jd) {
                    af[m][jd]     = (short)f2bf(alo[jd]);
                    af[m][4 + jd] = (short)f2bf(ahi[jd]);
                }
            }
            acc[0][0] = __builtin_amdgcn_mfma_f32_16x16x32_bf16(af[0], wcur[0], acc[0][0], 0, 0, 0);
            acc[0][1] = __builtin_amdgcn_mfma_f32_16x16x32_bf16(af[0], wcur[1], acc[0][1], 0, 0, 0);
            acc[1][0] = __builtin_amdgcn_mfma_f32_16x16x32_bf16(af[1], wcur[0], acc[1][0], 0, 0, 0);
            acc[1][1] = __builtin_amdgcn_mfma_f32_16x16x32_bf16(af[1], wcur[1], acc[1][1], 0, 0, 0);
            wcur[0] = wnxt[0];
            wcur[1] = wnxt[1];
        }
        // window boundary: next window's data must be landed everywhere
        asm volatile("s_waitcnt vmcnt(0)" ::: "memory");
        __builtin_amdgcn_sched_barrier(0);
        __builtin_amdgcn_s_barrier();
    }
    #undef ISSUE

    // ---- epilogue (v7-proven): sp in regs, LDS transpose, contiguous stores
    float spv[2][2][4];
    #pragma unroll
    for (int ni = 0; ni < 2; ++ni) {
        const float bb = bias[colBase + ni * 16 + lr];
        #pragma unroll
        for (int mi = 0; mi < 2; ++mi)
            #pragma unroll
            for (int r = 0; r < 4; ++r)
                spv[mi][ni][r] = fminf(fmaxf(acc[mi][ni][r] + bb, -1.f), 1.f);
    }

    typedef float OtRow[264];
    OtRow* Ot = reinterpret_cast<OtRow*>(smem);   // 33.8 KB reuse

    const int erow = tid >> 4;          // 0..31
    const int ecol = (tid & 15) * 4;    // 0..60
    const size_t GOFF = (size_t)M_TOT * L_SZ;
    float* orow = out + (size_t)(rowBase + erow) * L_SZ;

    // pass 1: sp
    #pragma unroll
    for (int ni = 0; ni < 2; ++ni)
        #pragma unroll
        for (int mi = 0; mi < 2; ++mi)
            #pragma unroll
            for (int r = 0; r < 4; ++r)
                Ot[mi * 16 + kseg * 4 + r][colBase + ni * 16 + lr] = spv[mi][ni][r];
    __syncthreads();
    #pragma unroll
    for (int j = 0; j < 4; ++j) {
        const f32x4 v = *reinterpret_cast<const f32x4*>(&Ot[erow][ecol + 64 * j]);
        *reinterpret_cast<f32x4*>(orow + ecol + 64 * j) = v;
    }
    __syncthreads();

    // pass 2: gini
    #pragma unroll
    for (int ni = 0; ni < 2; ++ni) {
        const int col = colBase + ni * 16 + lr;
        #pragma unroll
        for (int mi = 0; mi < 2; ++mi)
            #pragma unroll
            for (int r = 0; r < 4; ++r) {
                const int t = (rowBase + mi * 16 + kseg * 4 + r) & (T_SZ - 1);
                const float d  = spv[mi][ni][r] * cdiff[t * L_SZ + col];
                const float ed = __expf(d);
                const float s2 = ed / (1.f + ed);
                Ot[mi * 16 + kseg * 4 + r][col] = fmaf(2.f * s2, 1.f - s2, 1.f);
            }
    }
    __syncthreads();
    #pragma unroll
    for (int j = 0; j < 4; ++j) {
        const f32x4 v = *reinterpret_cast<const f32x4*>(&Ot[erow][ecol + 64 * j]);
        *reinterpret_cast<f32x4*>(orow + GOFF + ecol + 64 * j) = v;
    }
}

// ---------------- v1 fallback (no workspace needed) ------------------------
__global__ __launch_bounds__(512) void dn_fused_v1(
    const float* __restrict__ x, const float* __restrict__ W,
    const float* __restrict__ bias, const float* __restrict__ contrib,
    float* __restrict__ out)
{
    __shared__ bf16x8 As[4][128];
    __shared__ bf16x8 Bs[4][L_SZ];

    const int tid    = threadIdx.x;
    const int lane   = tid & 63;
    const int wid    = tid >> 6;
    const int waveM  = wid >> 2;
    const int waveN  = wid & 3;
    const int blkRow = blockIdx.x * 128;
    const int ar = tid >> 2;
    const int ak = (tid & 3) * 8;
    const int wr = tid >> 1;
    const int wk = (tid & 1) * 16;
    const int laneRow = lane & 15;
    const int kgrp    = lane >> 4;

    f32x4 acc[4][4];
    #pragma unroll
    for (int i = 0; i < 4; ++i)
        #pragma unroll
        for (int j = 0; j < 4; ++j)
            acc[i][j] = (f32x4){0.f, 0.f, 0.f, 0.f};

    const float* xrow = x + (size_t)(blkRow + ar) * F_SZ;
    const float* wrow = W + (size_t)wr * F_SZ;
    const f32x4 zf = {0.f, 0.f, 0.f, 0.f};

    f32x4 xa0 = *reinterpret_cast<const f32x4*>(xrow + ak);
    f32x4 xa1 = *reinterpret_cast<const f32x4*>(xrow + ak + 4);
    f32x4 wa0 = *reinterpret_cast<const f32x4*>(wrow + wk);
    f32x4 wa1 = *reinterpret_cast<const f32x4*>(wrow + wk + 4);
    f32x4 wa2 = *reinterpret_cast<const f32x4*>(wrow + wk + 8);
    f32x4 wa3 = *reinterpret_cast<const f32x4*>(wrow + wk + 12);

    for (int ks = 0; ks < KSTEPS; ++ks) {
        bf16x8 av, wv0, wv1;
        #pragma unroll
        for (int j = 0; j < 4; ++j) {
            av[j]      = (short)f2bf(xa0[j]);
            av[4 + j]  = (short)f2bf(xa1[j]);
            wv0[j]     = (short)f2bf(wa0[j]);
            wv0[4 + j] = (short)f2bf(wa1[j]);
            wv1[j]     = (short)f2bf(wa2[j]);
            wv1[4 + j] = (short)f2bf(wa3[j]);
        }
        As[ak >> 3][ar] = av;
        Bs[wk >> 3][wr] = wv0;
        Bs[(wk >> 3) + 1][wr] = wv1;
        __syncthreads();

        if (ks + 1 < KSTEPS) {
            const int kb = (ks + 1) * BK;
            if (kb + ak < F_SZ) {
                xa0 = *reinterpret_cast<const f32x4*>(xrow + kb + ak);
                xa1 = *reinterpret_cast<const f32x4*>(xrow + kb + ak + 4);
            } else { xa0 = zf; xa1 = zf; }
            if (kb + wk < F_SZ) {
                wa0 = *reinterpret_cast<const f32x4*>(wrow + kb + wk);
                wa1 = *reinterpret_cast<const f32x4*>(wrow + kb + wk + 4);
                wa2 = *reinterpret_cast<const f32x4*>(wrow + kb + wk + 8);
                wa3 = *reinterpret_cast<const f32x4*>(wrow + kb + wk + 12);
            } else { wa0 = zf; wa1 = zf; wa2 = zf; wa3 = zf; }
        }

        bf16x8 af[4], bfv[4];
        #pragma unroll
        for (int mi = 0; mi < 4; ++mi)
            af[mi] = As[kgrp][waveM * 64 + mi * 16 + laneRow];
        #pragma unroll
        for (int ni = 0; ni < 4; ++ni)
            bfv[ni] = Bs[kgrp][waveN * 64 + ni * 16 + laneRow];
        #pragma unroll
        for (int mi = 0; mi < 4; ++mi)
            #pragma unroll
            for (int ni = 0; ni < 4; ++ni)
                acc[mi][ni] = __builtin_amdgcn_mfma_f32_16x16x32_bf16(
                    af[mi], bfv[ni], acc[mi][ni], 0, 0, 0);
        __syncthreads();
    }

    const size_t GOFF  = (size_t)M_TOT * L_SZ;
    const int    rbase = waveM * 64 + (lane >> 4) * 4;
    const int    cbase = waveN * 64 + laneRow;
    #pragma unroll
    for (int ni = 0; ni < 4; ++ni) {
        const int col = cbase + ni * 16;
        const float bb = bias[col];
        #pragma unroll
        for (int mi = 0; mi < 4; ++mi) {
            #pragma unroll
            for (int r = 0; r < 4; ++r) {
                const int m = blkRow + rbase + mi * 16 + r;
                const int t = m & (T_SZ - 1);
                float v  = acc[mi][ni][r] + bb;
                float sp = fminf(fmaxf(v, -1.f), 1.f);
                const float* cp = contrib + (size_t)(t * L_SZ + col) * 2;
                const float d  = sp * (cp[0] - cp[1]);
                const float ed = __expf(d);
                const float s  = ed / (1.f + ed);
                const float g  = fmaf(2.f * s, 1.f - s, 1.f);
                const size_t o = (size_t)m * L_SZ + col;
                out[o]        = sp;
                out[GOFF + o] = g;
            }
        }
    }
}

extern "C" void kernel_launch(void* const* d_in, const int* in_sizes, int n_in,
                              void* d_out, int out_size, void* d_ws, size_t ws_size,
                              hipStream_t stream) {
    const float* x       = (const float*)d_in[0];
    const float* W       = (const float*)d_in[1];
    const float* bias    = (const float*)d_in[2];
    const float* contrib = (const float*)d_in[3];
    float* out = (float*)d_out;

    if (ws_size >= (size_t)WS_NEED && d_ws != nullptr) {
        unsigned short* wpre  = (unsigned short*)d_ws;
        float*          cdiff = (float*)((char*)d_ws + WPRE_BYTES);
        const int prep_threads = WPRE_ELEMS + CDIFF_ELEMS;
        dn_prep<<<(prep_threads + 255) / 256, 256, 0, stream>>>(W, contrib, wpre, cdiff);
        dn_fused12<<<M_TOT / 32, 512, 0, stream>>>(x, wpre, bias, cdiff, out);
    } else {
        dn_fused_v1<<<M_TOT / 128, 512, 0, stream>>>(x, W, bias, contrib, out);
    }
}

// Round 14
// 187.649 us; speedup vs baseline: 1.6928x; 1.0126x over previous
//
#include <hip/hip_runtime.h>
#include <hip/hip_bf16.h>

typedef __attribute__((ext_vector_type(8))) short bf16x8;
typedef __attribute__((ext_vector_type(4))) float f32x4;

#define B_SZ   1024
#define T_SZ   128
#define L_SZ   256
#define F_SZ   784
#define M_TOT  (B_SZ * T_SZ)            // 131072
#define BK     32
#define KSTEPS 25                       // ceil(784/32), tail zero-padded

#define WPRE_ELEMS (KSTEPS * 4 * L_SZ)  // 25600 bf16x8 elements
#define WPRE_BYTES (WPRE_ELEMS * 16)    // 409600
#define CDIFF_ELEMS (T_SZ * L_SZ)       // 32768
#define WS_NEED (WPRE_BYTES + CDIFF_ELEMS * 4)

// v13 geometry: f32 stage window = 32 rows x 160 f32 (5 K-steps), pitch 656B
#define ROWB    656                     // 640 data + 16 pad (bank rotation)
#define ABF_OFF 21504                   // f32S = 21 x 1024B DMA chunks
#define SMEM_SZ 33792                   // max(21504 + 20*33*16, Ot 32*264*4)

__device__ __forceinline__ unsigned short f2bf(float f) {
    __hip_bfloat16 h = __float2bfloat16(f);   // RTNE
    return *reinterpret_cast<unsigned short*>(&h);
}

// ---------------- prep: W -> bf16 MFMA-fragment layout; cdiff = c0 - c1 ----
// wpre[ks][kgrp][leaf] : bf16x8 = W[leaf][ks*32+kgrp*8 .. +8), 0-padded tail
__global__ __launch_bounds__(256) void dn_prep(
    const float* __restrict__ W, const float* __restrict__ contrib,
    unsigned short* __restrict__ wpre, float* __restrict__ cdiff)
{
    const int gid = blockIdx.x * 256 + threadIdx.x;
    if (gid < WPRE_ELEMS) {
        const int leaf = gid & 255;
        const int kg   = (gid >> 8) & 3;
        const int ks   = gid >> 10;
        const int k0   = ks * BK + kg * 8;
        bf16x8 v;
        #pragma unroll
        for (int j = 0; j < 8; ++j) {
            const int k = k0 + j;
            const float f = (k < F_SZ) ? W[(size_t)leaf * F_SZ + k] : 0.f;
            v[j] = (short)f2bf(f);
        }
        *reinterpret_cast<bf16x8*>(wpre + (size_t)gid * 8) = v;
    } else {
        const int cid = gid - WPRE_ELEMS;
        if (cid < CDIFF_ELEMS)
            cdiff[cid] = contrib[(size_t)cid * 2] - contrib[(size_t)cid * 2 + 1];
    }
}

// ---------------- v13: window DMA overlap + cvt-once bf16 tile -------------
// Block = 32 rows x 256 cols, 512 thr, 8 waves (wave tile 32x32). Grid 4096.
// Per window (5 K-steps): DMA for window w+1 streams into the single 21KB
// f32 buffer UNDER window w's compute; at the boundary, a ~1us CVT phase
// converts f32S -> Abf bf16 tile (each element converted ONCE — v12 paid
// 8x inside the K-loop). K-loop cost is thus identical to v8's (2 ds_read
// + 2 W-L2 loads + 4 MFMA per wave-step, zero cvts), while x HBM reads
// overlap MFMA + L2 traffic. Window-depth pipelining drains at each
// boundary by design, so plain __syncthreads() is correct (its vmcnt(0)
// is exactly the landing guarantee for the window DMA).
// Abf layout [kc][33 rows] (pad 33): cvt writes 528B stride = 2-way (free),
// frag reads = 16-lane contiguous 256B (v8-proven conflict-free).
// LDS 33.8KB -> 3 blocks/CU (24 waves).

#define GLDS(g, l)                                                           \
    __builtin_amdgcn_global_load_lds(                                        \
        (const __attribute__((address_space(1))) void*)(g),                  \
        (__attribute__((address_space(3))) void*)(l), 16, 0, 0)

__global__ __launch_bounds__(512, 6) void dn_fused13(
    const float* __restrict__ x, const unsigned short* __restrict__ wpre,
    const float* __restrict__ bias, const float* __restrict__ cdiff,
    float* __restrict__ out)
{
    __shared__ __align__(16) unsigned char smem[SMEM_SZ];

    const int tid  = threadIdx.x;
    const int lane = tid & 63;
    const int wid  = tid >> 6;          // 0..7 -> 32-col group
    const int lr   = lane & 15;
    const int kseg = lane >> 4;         // 0..3

    const int rowBase = blockIdx.x * 32;
    const int colBase = wid * 32;

    // ---- per-lane DMA sources: instr j covers f32S bytes [j*1024,+1024) ----
    const char* xb = (const char*)x;
    const char* srcB[3];   // window-0 source (+ w*640 per window)
    const char* srcC[3];   // clamped to row start (pad/tail lanes, valid floats)
    bool        v4[3];     // window-4 validity (source col < 3136)
    #pragma unroll
    for (int jj = 0; jj < 3; ++jj) {
        const int j = wid + 8 * jj;
        const unsigned s    = j * 1024 + lane * 16;
        const unsigned row  = s / ROWB;
        const unsigned colb = s - row * ROWB;
        const bool     ok   = (row < 32) && (colb < 640);
        const unsigned rcl  = (row < 32) ? row : 0;
        srcC[jj] = xb + (size_t)(rowBase + rcl) * 3136;
        srcB[jj] = srcC[jj] + (ok ? colb : 0);
        v4[jj]   = ok && (colb < 576);           // 2560+colb < 3136
    }

    #define ISSUE(w) do {                                                    \
        _Pragma("unroll")                                                    \
        for (int _jj = 0; _jj < 3; ++_jj) {                                  \
            const int _j = wid + 8 * _jj;                                    \
            if (_j < 21) {                                                   \
                const char* _s = ((w) < 4) ? (srcB[_jj] + (w) * 640)         \
                                : (v4[_jj] ? srcB[_jj] + 2560 : srcC[_jj]);  \
                GLDS(_s, smem + _j * 1024);                                  \
            }                                                                \
        }                                                                    \
    } while (0)

    // ---- CVT: f32S window -> Abf bf16 (each element converted once) ----
    #define CVT() do {                                                       \
        _Pragma("unroll")                                                    \
        for (int _h = 0; _h < 2; ++_h) {                                     \
            const int _c = tid + _h * 512;                                   \
            if (_c < 640) {                                                  \
                const int _row = _c / 20;                                    \
                const int _kc  = _c - _row * 20;                             \
                const f32x4 _lo = *reinterpret_cast<const f32x4*>(           \
                    smem + _row * ROWB + _kc * 32);                          \
                const f32x4 _hi = *reinterpret_cast<const f32x4*>(           \
                    smem + _row * ROWB + _kc * 32 + 16);                     \
                bf16x8 _v;                                                   \
                _Pragma("unroll")                                            \
                for (int _j = 0; _j < 4; ++_j) {                             \
                    _v[_j]     = (short)f2bf(_lo[_j]);                       \
                    _v[4 + _j] = (short)f2bf(_hi[_j]);                       \
                }                                                            \
                *reinterpret_cast<bf16x8*>(smem + ABF_OFF                    \
                    + (_kc * 33 + _row) * 16) = _v;                          \
            }                                                                \
        }                                                                    \
    } while (0)

    f32x4 acc[2][2];
    #pragma unroll
    for (int mi = 0; mi < 2; ++mi)
        #pragma unroll
        for (int ni = 0; ni < 2; ++ni)
            acc[mi][ni] = (f32x4){0.f, 0.f, 0.f, 0.f};

    const unsigned short* wpb = wpre + ((size_t)kseg * L_SZ + colBase + lr) * 8;
    bf16x8 wcur[2], wnxt[2];

    // prologue: land window 0, convert it, start window-1 DMA
    ISSUE(0);
    wcur[0] = *reinterpret_cast<const bf16x8*>(wpb);
    wcur[1] = *reinterpret_cast<const bf16x8*>(wpb + 128);
    __syncthreads();                    // vmcnt(0): window 0 landed
    CVT();
    __syncthreads();                    // Abf visible, f32S free
    ISSUE(1);

    #pragma unroll
    for (int w = 0; w < 5; ++w) {
        // compute 5 K-steps from Abf (DMA for w+1 flying underneath)
        #pragma unroll
        for (int i = 0; i < 5; ++i) {
            const int ks = w * 5 + i;
            if (ks + 1 < KSTEPS) {
                wnxt[0] = *reinterpret_cast<const bf16x8*>(wpb + (size_t)(ks + 1) * 8192);
                wnxt[1] = *reinterpret_cast<const bf16x8*>(wpb + (size_t)(ks + 1) * 8192 + 128);
            }
            bf16x8 af[2];
            #pragma unroll
            for (int m = 0; m < 2; ++m)
                af[m] = *reinterpret_cast<const bf16x8*>(
                    smem + ABF_OFF + (((i * 4 + kseg) * 33) + m * 16 + lr) * 16);

            acc[0][0] = __builtin_amdgcn_mfma_f32_16x16x32_bf16(af[0], wcur[0], acc[0][0], 0, 0, 0);
            acc[0][1] = __builtin_amdgcn_mfma_f32_16x16x32_bf16(af[0], wcur[1], acc[0][1], 0, 0, 0);
            acc[1][0] = __builtin_amdgcn_mfma_f32_16x16x32_bf16(af[1], wcur[0], acc[1][0], 0, 0, 0);
            acc[1][1] = __builtin_amdgcn_mfma_f32_16x16x32_bf16(af[1], wcur[1], acc[1][1], 0, 0, 0);
            wcur[0] = wnxt[0];
            wcur[1] = wnxt[1];
        }
        if (w < 4) {
            __syncthreads();            // vmcnt(0): window w+1 landed; Abf reads done
            CVT();
            __syncthreads();            // Abf updated, f32S free
            if (w < 3) ISSUE(w + 2);
        }
    }
    #undef ISSUE
    #undef CVT

    // ---- epilogue (v7/v8-proven): sp in regs, LDS transpose, full-line stores
    float spv[2][2][4];
    #pragma unroll
    for (int ni = 0; ni < 2; ++ni) {
        const float bb = bias[colBase + ni * 16 + lr];
        #pragma unroll
        for (int mi = 0; mi < 2; ++mi)
            #pragma unroll
            for (int r = 0; r < 4; ++r)
                spv[mi][ni][r] = fminf(fmaxf(acc[mi][ni][r] + bb, -1.f), 1.f);
    }

    typedef float OtRow[264];
    OtRow* Ot = reinterpret_cast<OtRow*>(smem);

    const int erow = tid >> 4;          // 0..31
    const int ecol = (tid & 15) * 4;    // 0..60
    const size_t GOFF = (size_t)M_TOT * L_SZ;
    float* orow = out + (size_t)(rowBase + erow) * L_SZ;

    __syncthreads();                    // K-loop LDS dead; reuse as Ot

    // pass 1: sp
    #pragma unroll
    for (int ni = 0; ni < 2; ++ni)
        #pragma unroll
        for (int mi = 0; mi < 2; ++mi)
            #pragma unroll
            for (int r = 0; r < 4; ++r)
                Ot[mi * 16 + kseg * 4 + r][colBase + ni * 16 + lr] = spv[mi][ni][r];
    __syncthreads();
    #pragma unroll
    for (int j = 0; j < 4; ++j) {
        const f32x4 v = *reinterpret_cast<const f32x4*>(&Ot[erow][ecol + 64 * j]);
        *reinterpret_cast<f32x4*>(orow + ecol + 64 * j) = v;
    }
    __syncthreads();

    // pass 2: gini
    #pragma unroll
    for (int ni = 0; ni < 2; ++ni) {
        const int col = colBase + ni * 16 + lr;
        #pragma unroll
        for (int mi = 0; mi < 2; ++mi)
            #pragma unroll
            for (int r = 0; r < 4; ++r) {
                const int t = (rowBase + mi * 16 + kseg * 4 + r) & (T_SZ - 1);
                const float d  = spv[mi][ni][r] * cdiff[t * L_SZ + col];
                const float ed = __expf(d);
                const float s2 = ed / (1.f + ed);
                Ot[mi * 16 + kseg * 4 + r][col] = fmaf(2.f * s2, 1.f - s2, 1.f);
            }
    }
    __syncthreads();
    #pragma unroll
    for (int j = 0; j < 4; ++j) {
        const f32x4 v = *reinterpret_cast<const f32x4*>(&Ot[erow][ecol + 64 * j]);
        *reinterpret_cast<f32x4*>(orow + GOFF + ecol + 64 * j) = v;
    }
}

// ---------------- v1 fallback (no workspace needed) ------------------------
__global__ __launch_bounds__(512) void dn_fused_v1(
    const float* __restrict__ x, const float* __restrict__ W,
    const float* __restrict__ bias, const float* __restrict__ contrib,
    float* __restrict__ out)
{
    __shared__ bf16x8 As[4][128];
    __shared__ bf16x8 Bs[4][L_SZ];

    const int tid    = threadIdx.x;
    const int lane   = tid & 63;
    const int wid    = tid >> 6;
    const int waveM  = wid >> 2;
    const int waveN  = wid & 3;
    const int blkRow = blockIdx.x * 128;
    const int ar = tid >> 2;
    const int ak = (tid & 3) * 8;
    const int wr = tid >> 1;
    const int wk = (tid & 1) * 16;
    const int laneRow = lane & 15;
    const int kgrp    = lane >> 4;

    f32x4 acc[4][4];
    #pragma unroll
    for (int i = 0; i < 4; ++i)
        #pragma unroll
        for (int j = 0; j < 4; ++j)
            acc[i][j] = (f32x4){0.f, 0.f, 0.f, 0.f};

    const float* xrow = x + (size_t)(blkRow + ar) * F_SZ;
    const float* wrow = W + (size_t)wr * F_SZ;
    const f32x4 zf = {0.f, 0.f, 0.f, 0.f};

    f32x4 xa0 = *reinterpret_cast<const f32x4*>(xrow + ak);
    f32x4 xa1 = *reinterpret_cast<const f32x4*>(xrow + ak + 4);
    f32x4 wa0 = *reinterpret_cast<const f32x4*>(wrow + wk);
    f32x4 wa1 = *reinterpret_cast<const f32x4*>(wrow + wk + 4);
    f32x4 wa2 = *reinterpret_cast<const f32x4*>(wrow + wk + 8);
    f32x4 wa3 = *reinterpret_cast<const f32x4*>(wrow + wk + 12);

    for (int ks = 0; ks < KSTEPS; ++ks) {
        bf16x8 av, wv0, wv1;
        #pragma unroll
        for (int j = 0; j < 4; ++j) {
            av[j]      = (short)f2bf(xa0[j]);
            av[4 + j]  = (short)f2bf(xa1[j]);
            wv0[j]     = (short)f2bf(wa0[j]);
            wv0[4 + j] = (short)f2bf(wa1[j]);
            wv1[j]     = (short)f2bf(wa2[j]);
            wv1[4 + j] = (short)f2bf(wa3[j]);
        }
        As[ak >> 3][ar] = av;
        Bs[wk >> 3][wr] = wv0;
        Bs[(wk >> 3) + 1][wr] = wv1;
        __syncthreads();

        if (ks + 1 < KSTEPS) {
            const int kb = (ks + 1) * BK;
            if (kb + ak < F_SZ) {
                xa0 = *reinterpret_cast<const f32x4*>(xrow + kb + ak);
                xa1 = *reinterpret_cast<const f32x4*>(xrow + kb + ak + 4);
            } else { xa0 = zf; xa1 = zf; }
            if (kb + wk < F_SZ) {
                wa0 = *reinterpret_cast<const f32x4*>(wrow + kb + wk);
                wa1 = *reinterpret_cast<const f32x4*>(wrow + kb + wk + 4);
                wa2 = *reinterpret_cast<const f32x4*>(wrow + kb + wk + 8);
                wa3 = *reinterpret_cast<const f32x4*>(wrow + kb + wk + 12);
            } else { wa0 = zf; wa1 = zf; wa2 = zf; wa3 = zf; }
        }

        bf16x8 af[4], bfv[4];
        #pragma unroll
        for (int mi = 0; mi < 4; ++mi)
            af[mi] = As[kgrp][waveM * 64 + mi * 16 + laneRow];
        #pragma unroll
        for (int ni = 0; ni < 4; ++ni)
            bfv[ni] = Bs[kgrp][waveN * 64 + ni * 16 + laneRow];
        #pragma unroll
        for (int mi = 0; mi < 4; ++mi)
            #pragma unroll
            for (int ni = 0; ni < 4; ++ni)
                acc[mi][ni] = __builtin_amdgcn_mfma_f32_16x16x32_bf16(
                    af[mi], bfv[ni], acc[mi][ni], 0, 0, 0);
        __syncthreads();
    }

    const size_t GOFF  = (size_t)M_TOT * L_SZ;
    const int    rbase = waveM * 64 + (lane >> 4) * 4;
    const int    cbase = waveN * 64 + laneRow;
    #pragma unroll
    for (int ni = 0; ni < 4; ++ni) {
        const int col = cbase + ni * 16;
        const float bb = bias[col];
        #pragma unroll
        for (int mi = 0; mi < 4; ++mi) {
            #pragma unroll
            for (int r = 0; r < 4; ++r) {
                const int m = blkRow + rbase + mi * 16 + r;
                const int t = m & (T_SZ - 1);
                float v  = acc[mi][ni][r] + bb;
                float sp = fminf(fmaxf(v, -1.f), 1.f);
                const float* cp = contrib + (size_t)(t * L_SZ + col) * 2;
                const float d  = sp * (cp[0] - cp[1]);
                const float ed = __expf(d);
                const float s  = ed / (1.f + ed);
                const float g  = fmaf(2.f * s, 1.f - s, 1.f);
                const size_t o = (size_t)m * L_SZ + col;
                out[o]        = sp;
                out[GOFF + o] = g;
            }
        }
    }
}

extern "C" void kernel_launch(void* const* d_in, const int* in_sizes, int n_in,
                              void* d_out, int out_size, void* d_ws, size_t ws_size,
                              hipStream_t stream) {
    const float* x       = (const float*)d_in[0];
    const float* W       = (const float*)d_in[1];
    const float* bias    = (const float*)d_in[2];
    const float* contrib = (const float*)d_in[3];
    float* out = (float*)d_out;

    if (ws_size >= (size_t)WS_NEED && d_ws != nullptr) {
        unsigned short* wpre  = (unsigned short*)d_ws;
        float*          cdiff = (float*)((char*)d_ws + WPRE_BYTES);
        const int prep_threads = WPRE_ELEMS + CDIFF_ELEMS;
        dn_prep<<<(prep_threads + 255) / 256, 256, 0, stream>>>(W, contrib, wpre, cdiff);
        dn_fused13<<<M_TOT / 32, 512, 0, stream>>>(x, wpre, bias, cdiff, out);
    } else {
        dn_fused_v1<<<M_TOT / 128, 512, 0, stream>>>(x, W, bias, contrib, out);
    }
}